// Round 12
// baseline (28374.866 us; speedup 1.0000x reference)
//
#include <hip/hip_runtime.h>
#include <hip/hip_fp16.h>

typedef _Float16 h8 __attribute__((ext_vector_type(8)));
typedef _Float16 h2 __attribute__((ext_vector_type(2)));
typedef float    f4 __attribute__((ext_vector_type(4)));
typedef unsigned int u32;
typedef u32 u32x4 __attribute__((ext_vector_type(4)));

#define HDIM 2048
#define FDIM 2048
#define TSEQ 4096
#define NR   8192   // 4*H rows of the fused gate matrix

__device__ __forceinline__ float sigmoidf_(float x) { return 1.0f / (1.0f + __expf(-x)); }
__device__ __forceinline__ float tanhf_(float x)    { return 1.0f - 2.0f / (1.0f + __expf(2.0f * x)); }

// Bank-swizzle for the LDS h-stage: 16B groups, low4 of group idx XOR'd with
// bits [7:4] -> reads at fixed i across cc spread over banks (2-4 way max).
__device__ __forceinline__ int swz(int g) { return (g & ~15) | ((g ^ (g >> 4)) & 15); }

// ---------------------------------------------------------------------------
// GEMM: Zx[t][j] = sum_k X[t][k] * w{g}[j&2047][2048+k],  g = j>>11
// M=4096(T) x N=8192(4H) x K=2048(F), fp16 MFMA 16x16x32, 128x128 tile.
// ---------------------------------------------------------------------------
__global__ __launch_bounds__(256) void gemm_zx(
    const float* __restrict__ X,
    const float* __restrict__ wfp, const float* __restrict__ wip,
    const float* __restrict__ wcp, const float* __restrict__ wop,
    _Float16* __restrict__ Zx)
{
    __shared__ __align__(16) _Float16 As[128 * 32];
    __shared__ __align__(16) _Float16 Bs[128 * 32];
    const int tid  = threadIdx.x;
    const int lane = tid & 63;
    const int wv   = tid >> 6;
    const int bm   = blockIdx.x & 31;   // 32 M-tiles
    const int bn   = blockIdx.x >> 5;   // 64 N-tiles
    const int m0 = bm * 128, n0 = bn * 128;
    const int g = n0 >> 11;             // 128-row tile never crosses a gate boundary
    const float* wsrc = (g == 0) ? wfp : (g == 1) ? wip : (g == 2) ? wcp : wop;
    const int nr0 = n0 & 2047;

    f4 acc[4][4];
    #pragma unroll
    for (int i = 0; i < 4; ++i)
        #pragma unroll
        for (int j = 0; j < 4; ++j) acc[i][j] = (f4){0.f, 0.f, 0.f, 0.f};

    const int wm = (wv >> 1) * 64, wn = (wv & 1) * 64;
    const int fr = lane & 15, kg = lane >> 4;

    for (int k0 = 0; k0 < FDIM; k0 += 32) {
        __syncthreads();
        #pragma unroll
        for (int r = 0; r < 2; ++r) {
            const int row = r * 64 + (tid >> 2);
            const int col = (tid & 3) * 8;
            const float* ax = &X[(size_t)(m0 + row) * FDIM + k0 + col];
            f4 a0 = *(const f4*)ax, a1 = *(const f4*)(ax + 4);
            h8 av = { (_Float16)a0[0], (_Float16)a0[1], (_Float16)a0[2], (_Float16)a0[3],
                      (_Float16)a1[0], (_Float16)a1[1], (_Float16)a1[2], (_Float16)a1[3] };
            *(h8*)&As[row * 32 + col] = av;
            const float* bx = &wsrc[(size_t)(nr0 + row) * 4096 + 2048 + k0 + col];
            f4 b0 = *(const f4*)bx, b1 = *(const f4*)(bx + 4);
            h8 bv = { (_Float16)b0[0], (_Float16)b0[1], (_Float16)b0[2], (_Float16)b0[3],
                      (_Float16)b1[0], (_Float16)b1[1], (_Float16)b1[2], (_Float16)b1[3] };
            *(h8*)&Bs[row * 32 + col] = bv;
        }
        __syncthreads();
        h8 af[4], bf[4];
        #pragma unroll
        for (int i = 0; i < 4; ++i) af[i] = *(const h8*)&As[(wm + i * 16 + fr) * 32 + kg * 8];
        #pragma unroll
        for (int j = 0; j < 4; ++j) bf[j] = *(const h8*)&Bs[(wn + j * 16 + fr) * 32 + kg * 8];
        #pragma unroll
        for (int i = 0; i < 4; ++i)
            #pragma unroll
            for (int j = 0; j < 4; ++j)
                acc[i][j] = __builtin_amdgcn_mfma_f32_16x16x32_f16(af[i], bf[j], acc[i][j], 0, 0, 0);
    }
    // C/D layout: col = lane&15 (N), row = (lane>>4)*4 + q (M)   [m89/m91]
    #pragma unroll
    for (int i = 0; i < 4; ++i)
        #pragma unroll
        for (int j = 0; j < 4; ++j)
            #pragma unroll
            for (int q = 0; q < 4; ++q) {
                const int row = m0 + wm + i * 16 + (lane >> 4) * 4 + q;
                const int col = n0 + wn + j * 16 + (lane & 15);
                Zx[(size_t)row * NR + col] = (_Float16)acc[i][j][q];
            }
}

// ---------------------------------------------------------------------------
// Persistent recurrent kernel: 256 WGs x 320 thr. Waves 0-3 (tid<256) = dot
// waves (8 h-rows/WG, R11 mapping: half rg owns all 4 gates of h-elem rg).
// Wave 4 (tid>=256) = COMM WAVE: while dot waves compute step t, it polls
// the NEXT step's sentinels (4 producers/lane, sc0 sc1) -> detect overlaps
// compute, Phase A's serial wait collapses into the barrier.
// Protocol (proven R4/R8): tag-in-word, hword 2 slots x 2048 u32, word j of
// slot (t&1) = (t<<16)|fp16bits(h_t[j]); publish via atomic_swap sc1; Phase B
// bulk fetch FULL-verifies every word (sentinel=>block visibility never
// assumed; stale words just re-fetch). Ring safety: publisher reaches t+2
// only after its Phase B consumed t. Iter 0's tags pre-verified by memset
// (slot0 = (tag0,h=0) == h_0). t=4095 polls tag 4096 -- published by every
// tail. Deadlock-safe residency: even 2 WGs/CU (10 waves @136 VGPR) stay
// resident by capacity. Weights in VGPRs (static 4x64 slice/thread).
// ---------------------------------------------------------------------------
__global__ __launch_bounds__(320, 1) void lstm_rec(
    const float* __restrict__ wfp, const float* __restrict__ wip,
    const float* __restrict__ wcp, const float* __restrict__ wop,
    const float* __restrict__ bfv, const float* __restrict__ biv,
    const float* __restrict__ bcv, const float* __restrict__ bov,
    const _Float16* __restrict__ Zx,
    u32* __restrict__ hword,          // 2 * 2048 tagged words
    float* __restrict__ hfin)         // 2048 fp32
{
    __shared__ __align__(16) u32 stage[HDIM];  // 8 KiB staged h words

    const int tid  = threadIdx.x;
    const int w    = blockIdx.x;
    const bool dotw = (tid < 256);
    const int rg   = (tid >> 5) & 7, cc = tid & 31;

    // ---- one-time (dot waves): weight slice into VGPRs (static indexing) ----
    h8 wreg[4][8];
    if (dotw) {
        #pragma unroll
        for (int q = 0; q < 4; ++q) {
            const float* src = ((q == 0) ? wfp : (q == 1) ? wip : (q == 2) ? wcp : wop)
                               + (size_t)(8 * w + rg) * 4096 + cc * 64;
            #pragma unroll
            for (int i = 0; i < 8; ++i) {
                f4 a0 = *(const f4*)(src + i * 8);
                f4 a1 = *(const f4*)(src + i * 8 + 4);
                wreg[q][i] = (h8){ (_Float16)a0[0], (_Float16)a0[1], (_Float16)a0[2], (_Float16)a0[3],
                                   (_Float16)a1[0], (_Float16)a1[1], (_Float16)a1[2], (_Float16)a1[3] };
            }
        }
    }
    // ---- publisher-lane (cc==0 of dot waves) params ----
    float bias0 = 0.f, bias1 = 0.f, bias2 = 0.f, bias3 = 0.f;
    float c_reg = 0.f;
    if (dotw && cc == 0) {
        bias0 = bfv[8 * w + rg]; bias1 = biv[8 * w + rg];
        bias2 = bcv[8 * w + rg]; bias3 = bov[8 * w + rg];
    }
    const _Float16* zxp = Zx + 8 * w + rg;   // + t*NR + q*2048

    #pragma unroll 1
    for (int t = 0; t < TSEQ; ++t) {
        const u32 texp = (u32)t << 16;
        const size_t slotbase = (size_t)(t & 1) * HDIM;

        if (dotw) {
            float zx0 = 0.f, zx1 = 0.f, zx2 = 0.f, zx3 = 0.f;
            if (cc == 0) {   // x-projection prefetch (plain loads, L2-warm)
                const _Float16* zp = zxp + (size_t)t * NR;
                zx0 = (float)zp[0];    zx1 = (float)zp[2048];
                zx2 = (float)zp[4096]; zx3 = (float)zp[6144];
            }
            // ---- Phase B: bulk fetch tag t (sentinels pre-verified) ----
            const u32* p = hword + slotbase + (size_t)tid * 8;
            u32x4 A, B;
            for (;;) {
                asm volatile(
                    "global_load_dwordx4 %0, %2, off sc0 sc1\n\t"
                    "global_load_dwordx4 %1, %2, off offset:16 sc0 sc1\n\t"
                    "s_waitcnt vmcnt(0)"
                    : "=&v"(A), "=&v"(B) : "v"(p) : "memory");
                const u32 bad = ((A.x ^ texp) | (A.y ^ texp) | (A.z ^ texp) | (A.w ^ texp) |
                                 (B.x ^ texp) | (B.y ^ texp) | (B.z ^ texp) | (B.w ^ texp))
                                & 0xFFFF0000u;
                if (!bad) break;
                __builtin_amdgcn_s_sleep(1);
            }
            *(u32x4*)&stage[swz(tid * 2) * 4]     = A;
            *(u32x4*)&stage[swz(tid * 2 + 1) * 4] = B;
            __syncthreads();   // stage ready

            // ---- dot: 4 gate-rows (of h-elem rg) x 64 cols per thread ----
            float acc[4] = {0.f, 0.f, 0.f, 0.f};
            #pragma unroll
            for (int i = 0; i < 8; ++i) {
                u32x4 ga = *(const u32x4*)&stage[swz(cc * 16 + 2 * i) * 4];
                u32x4 gb = *(const u32x4*)&stage[swz(cc * 16 + 2 * i + 1) * 4];
                const h2 h0  = __builtin_bit_cast(h2, (u32)((ga.x & 0xffffu) | (ga.y << 16)));
                const h2 h1  = __builtin_bit_cast(h2, (u32)((ga.z & 0xffffu) | (ga.w << 16)));
                const h2 h2v = __builtin_bit_cast(h2, (u32)((gb.x & 0xffffu) | (gb.y << 16)));
                const h2 h3  = __builtin_bit_cast(h2, (u32)((gb.z & 0xffffu) | (gb.w << 16)));
                #pragma unroll
                for (int q = 0; q < 4; ++q) {
                    const h8 wv8 = wreg[q][i];
                    acc[q] = __builtin_amdgcn_fdot2((h2){wv8[0], wv8[1]}, h0,  acc[q], false);
                    acc[q] = __builtin_amdgcn_fdot2((h2){wv8[2], wv8[3]}, h1,  acc[q], false);
                    acc[q] = __builtin_amdgcn_fdot2((h2){wv8[4], wv8[5]}, h2v, acc[q], false);
                    acc[q] = __builtin_amdgcn_fdot2((h2){wv8[6], wv8[7]}, h3,  acc[q], false);
                }
            }
            #pragma unroll
            for (int m = 16; m >= 1; m >>= 1) {
                #pragma unroll
                for (int q = 0; q < 4; ++q) acc[q] += __shfl_xor(acc[q], m, 64);
            }
            // ---- gate math + cell update + publish, lane cc==0 ----
            if (cc == 0) {
                const float f  = sigmoidf_(acc[0] + zx0 + bias0);
                const float i_ = sigmoidf_(acc[1] + zx1 + bias1);
                const float g_ = tanhf_(acc[2] + zx2 + bias2);
                const float o  = sigmoidf_(acc[3] + zx3 + bias3);
                const float cn = f * c_reg + i_ * g_;
                c_reg = cn;
                const float hn = o * tanhf_(cn);
                const unsigned short hb =
                    __builtin_bit_cast(unsigned short, (_Float16)hn);
                const u32 word = ((u32)(t + 1) << 16) | (u32)hb;
                u32* op = hword + (size_t)((t + 1) & 1) * HDIM + 8 * w + rg;
                asm volatile("global_atomic_swap %0, %1, off sc1"
                             :: "v"(op), "v"(word) : "memory");
                if (t == TSEQ - 1) hfin[8 * w + rg] = hn;
            }
        } else {
            __syncthreads();   // matches dot waves' stage barrier
            // ---- COMM WAVE: detect NEXT step's tags while dot waves compute ----
            const u32 nexp = (u32)(t + 1) << 16;
            const u32* sp = hword + (size_t)((t + 1) & 1) * HDIM + (size_t)(tid - 256) * 32;
            u32 s0, s1, s2, s3;
            for (;;) {
                asm volatile(
                    "global_load_dword %0, %4, off sc0 sc1\n\t"
                    "global_load_dword %1, %4, off offset:32 sc0 sc1\n\t"
                    "global_load_dword %2, %4, off offset:64 sc0 sc1\n\t"
                    "global_load_dword %3, %4, off offset:96 sc0 sc1\n\t"
                    "s_waitcnt vmcnt(0)"
                    : "=&v"(s0), "=&v"(s1), "=&v"(s2), "=&v"(s3)
                    : "v"(sp) : "memory");
                const u32 bad = ((s0 ^ nexp) | (s1 ^ nexp) | (s2 ^ nexp) | (s3 ^ nexp))
                                & 0xFFFF0000u;
                if (!bad) break;
            }
        }
        __syncthreads();   // next tags verified + stage consumption complete
    }
}

// ---------------------------------------------------------------------------
// y[row] = by[row] + wy[row,:] . hfin
// ---------------------------------------------------------------------------
__global__ __launch_bounds__(256) void proj(
    const float* __restrict__ wy, const float* __restrict__ byv,
    const float* __restrict__ hfin, float* __restrict__ y)
{
    const int row = blockIdx.x;
    const float* wr = wy + (size_t)row * HDIM;
    float s = 0.f;
    for (int k = threadIdx.x * 4; k < HDIM; k += 256 * 4) {
        f4 wv = *(const f4*)&wr[k];
        f4 hv = *(const f4*)&hfin[k];
        s = fmaf(wv[0], hv[0], fmaf(wv[1], hv[1], fmaf(wv[2], hv[2], fmaf(wv[3], hv[3], s))));
    }
    #pragma unroll
    for (int m = 32; m >= 1; m >>= 1) s += __shfl_xor(s, m, 64);
    __shared__ float red[4];
    if ((threadIdx.x & 63) == 0) red[threadIdx.x >> 6] = s;
    __syncthreads();
    if (threadIdx.x == 0) y[row] = red[0] + red[1] + red[2] + red[3] + byv[row];
}

// ---------------------------------------------------------------------------
extern "C" void kernel_launch(void* const* d_in, const int* in_sizes, int n_in,
                              void* d_out, int out_size, void* d_ws, size_t ws_size,
                              hipStream_t stream)
{
    (void)in_sizes; (void)n_in; (void)out_size;
    const float* X   = (const float*)d_in[0];
    const float* wfp = (const float*)d_in[1];
    const float* bfv = (const float*)d_in[2];
    const float* wip = (const float*)d_in[3];
    const float* biv = (const float*)d_in[4];
    const float* wcp = (const float*)d_in[5];
    const float* bcv = (const float*)d_in[6];
    const float* wop = (const float*)d_in[7];
    const float* bov = (const float*)d_in[8];
    const float* wy  = (const float*)d_in[9];
    const float* byv = (const float*)d_in[10];
    float* y = (float*)d_out;

    char* ws = (char*)d_ws;
    const size_t need = ((size_t)64 << 20) + ((size_t)64 << 10);
    if (ws_size < need) return;  // fail visibly rather than corrupt

    _Float16* Zx  = (_Float16*)ws;                                   // 64 MiB
    u32* hword    = (u32*)(ws + ((size_t)64 << 20));                 // 16 KiB
    float* hfin   = (float*)(ws + ((size_t)64 << 20) + (16 << 10));  // 8 KiB

    // slot0 = (tag 0, h=0) == correct h_0; also kills cross-replay tag aliasing
    (void)hipMemsetAsync(hword, 0, 2 * HDIM * sizeof(u32), stream);
    gemm_zx<<<dim3(2048), dim3(256), 0, stream>>>(X, wfp, wip, wcp, wop, Zx);
    lstm_rec<<<dim3(256), dim3(320), 0, stream>>>(wfp, wip, wcp, wop,
                                                  bfv, biv, bcv, bov,
                                                  Zx, hword, hfin);
    proj<<<dim3(2048), dim3(256), 0, stream>>>(wy, byv, hfin, y);
}

// Round 13
// 22558.865 us; speedup vs baseline: 1.2578x; 1.2578x over previous
//
#include <hip/hip_runtime.h>
#include <hip/hip_fp16.h>

typedef _Float16 h8 __attribute__((ext_vector_type(8)));
typedef _Float16 h2 __attribute__((ext_vector_type(2)));
typedef float    f4 __attribute__((ext_vector_type(4)));
typedef unsigned int u32;
typedef u32 u32x4 __attribute__((ext_vector_type(4)));

#define HDIM 2048
#define FDIM 2048
#define TSEQ 4096
#define NR   8192   // 4*H rows of the fused gate matrix

__device__ __forceinline__ float sigmoidf_(float x) { return 1.0f / (1.0f + __expf(-x)); }
__device__ __forceinline__ float tanhf_(float x)    { return 1.0f - 2.0f / (1.0f + __expf(2.0f * x)); }

// Bank-swizzle for the LDS h-stage: 16B groups, low4 of group idx XOR'd with
// bits [7:4] -> reads at fixed i across cc spread over banks (2-4 way max).
__device__ __forceinline__ int swz(int g) { return (g & ~15) | ((g ^ (g >> 4)) & 15); }

// ---------------------------------------------------------------------------
// GEMM: Zx[t][j] = sum_k X[t][k] * w{g}[j&2047][2048+k],  g = j>>11
// M=4096(T) x N=8192(4H) x K=2048(F), fp16 MFMA 16x16x32, 128x128 tile.
// ---------------------------------------------------------------------------
__global__ __launch_bounds__(256) void gemm_zx(
    const float* __restrict__ X,
    const float* __restrict__ wfp, const float* __restrict__ wip,
    const float* __restrict__ wcp, const float* __restrict__ wop,
    _Float16* __restrict__ Zx)
{
    __shared__ __align__(16) _Float16 As[128 * 32];
    __shared__ __align__(16) _Float16 Bs[128 * 32];
    const int tid  = threadIdx.x;
    const int lane = tid & 63;
    const int wv   = tid >> 6;
    const int bm   = blockIdx.x & 31;   // 32 M-tiles
    const int bn   = blockIdx.x >> 5;   // 64 N-tiles
    const int m0 = bm * 128, n0 = bn * 128;
    const int g = n0 >> 11;             // 128-row tile never crosses a gate boundary
    const float* wsrc = (g == 0) ? wfp : (g == 1) ? wip : (g == 2) ? wcp : wop;
    const int nr0 = n0 & 2047;

    f4 acc[4][4];
    #pragma unroll
    for (int i = 0; i < 4; ++i)
        #pragma unroll
        for (int j = 0; j < 4; ++j) acc[i][j] = (f4){0.f, 0.f, 0.f, 0.f};

    const int wm = (wv >> 1) * 64, wn = (wv & 1) * 64;
    const int fr = lane & 15, kg = lane >> 4;

    for (int k0 = 0; k0 < FDIM; k0 += 32) {
        __syncthreads();
        #pragma unroll
        for (int r = 0; r < 2; ++r) {
            const int row = r * 64 + (tid >> 2);
            const int col = (tid & 3) * 8;
            const float* ax = &X[(size_t)(m0 + row) * FDIM + k0 + col];
            f4 a0 = *(const f4*)ax, a1 = *(const f4*)(ax + 4);
            h8 av = { (_Float16)a0[0], (_Float16)a0[1], (_Float16)a0[2], (_Float16)a0[3],
                      (_Float16)a1[0], (_Float16)a1[1], (_Float16)a1[2], (_Float16)a1[3] };
            *(h8*)&As[row * 32 + col] = av;
            const float* bx = &wsrc[(size_t)(nr0 + row) * 4096 + 2048 + k0 + col];
            f4 b0 = *(const f4*)bx, b1 = *(const f4*)(bx + 4);
            h8 bv = { (_Float16)b0[0], (_Float16)b0[1], (_Float16)b0[2], (_Float16)b0[3],
                      (_Float16)b1[0], (_Float16)b1[1], (_Float16)b1[2], (_Float16)b1[3] };
            *(h8*)&Bs[row * 32 + col] = bv;
        }
        __syncthreads();
        h8 af[4], bf[4];
        #pragma unroll
        for (int i = 0; i < 4; ++i) af[i] = *(const h8*)&As[(wm + i * 16 + fr) * 32 + kg * 8];
        #pragma unroll
        for (int j = 0; j < 4; ++j) bf[j] = *(const h8*)&Bs[(wn + j * 16 + fr) * 32 + kg * 8];
        #pragma unroll
        for (int i = 0; i < 4; ++i)
            #pragma unroll
            for (int j = 0; j < 4; ++j)
                acc[i][j] = __builtin_amdgcn_mfma_f32_16x16x32_f16(af[i], bf[j], acc[i][j], 0, 0, 0);
    }
    // C/D layout: col = lane&15 (N), row = (lane>>4)*4 + q (M)   [m89/m91]
    #pragma unroll
    for (int i = 0; i < 4; ++i)
        #pragma unroll
        for (int j = 0; j < 4; ++j)
            #pragma unroll
            for (int q = 0; q < 4; ++q) {
                const int row = m0 + wm + i * 16 + (lane >> 4) * 4 + q;
                const int col = n0 + wn + j * 16 + (lane & 15);
                Zx[(size_t)row * NR + col] = (_Float16)acc[i][j][q];
            }
}

// ---------------------------------------------------------------------------
// Persistent recurrent kernel (256 WGs x 256 thr, 8 h-rows per WG), fence-free
// tag-in-word messaging. hword: 2 slots x 2048 u32; word j of slot (t&1) =
// (t<<16)|fp16bits(h_t[j]). Publish: atomic_swap sc1 from cc==0 lanes (R11
// in-lane tail; half rg owns all 4 gates of h-elem rg).
// ONE barrier per step:
//   [bar: stage(t) ready] -> dot -> shfl reduce -> cc==0: gates/cell/publish
//   t+1 -> wave 0 alone: LATE-burst sentinel detect (64 lanes x 4 producers,
//   sc0 sc1, R8 timing: poll starts only after local tail) -> fetch the full
//   8KB itself (8 dwordx4/lane) with FULL per-word tag verify (retry on any
//   stale word; correctness never rests on sentinel=>block visibility) ->
//   write stage(t+1).
// Safety: wave0 overwrites stage only after detecting ALL t+1 publishes,
// which require every WG's dot(t) complete -> stage(t) fully consumed.
// Ring safety: our publishers (all 4 waves) publish t+1 only after our dot
// consumed t; the same induction as R4/R8 forbids tag t+2 before global
// consumption of t. Pre-loop stages zeros (== h_0); hword memset per launch
// kills cross-replay tag aliasing. Weights in VGPRs (4x64 slice/thread).
// ---------------------------------------------------------------------------
__global__ __launch_bounds__(256, 1) void lstm_rec(
    const float* __restrict__ wfp, const float* __restrict__ wip,
    const float* __restrict__ wcp, const float* __restrict__ wop,
    const float* __restrict__ bfv, const float* __restrict__ biv,
    const float* __restrict__ bcv, const float* __restrict__ bov,
    const _Float16* __restrict__ Zx,
    u32* __restrict__ hword,          // 2 * 2048 tagged words
    float* __restrict__ hfin)         // 2048 fp32
{
    __shared__ __align__(16) u32 stage[HDIM];  // 8 KiB staged h words

    const int tid = threadIdx.x;
    const int w   = blockIdx.x;
    const int rg  = tid >> 5, cc = tid & 31;   // half rg owns h-elem (8w+rg)

    // ---- one-time: weight slice into VGPRs. q = gate, elem = rg, cols cc*64+ ----
    h8 wreg[4][8];
    #pragma unroll
    for (int q = 0; q < 4; ++q) {
        const float* src = ((q == 0) ? wfp : (q == 1) ? wip : (q == 2) ? wcp : wop)
                           + (size_t)(8 * w + rg) * 4096 + cc * 64;
        #pragma unroll
        for (int i = 0; i < 8; ++i) {
            f4 a0 = *(const f4*)(src + i * 8);
            f4 a1 = *(const f4*)(src + i * 8 + 4);
            wreg[q][i] = (h8){ (_Float16)a0[0], (_Float16)a0[1], (_Float16)a0[2], (_Float16)a0[3],
                               (_Float16)a1[0], (_Float16)a1[1], (_Float16)a1[2], (_Float16)a1[3] };
        }
    }
    // ---- publisher-lane (cc==0) params: biases + cell state + Zx base ----
    float bias0 = 0.f, bias1 = 0.f, bias2 = 0.f, bias3 = 0.f;
    float c_reg = 0.f;
    if (cc == 0) {
        bias0 = bfv[8 * w + rg]; bias1 = biv[8 * w + rg];
        bias2 = bcv[8 * w + rg]; bias3 = bov[8 * w + rg];
    }
    const _Float16* zxp = Zx + 8 * w + rg;   // + t*NR + q*2048

    // ---- pre-loop: stage h_0 = 0 (slot0 words are (tag0, 0) by memset) ----
    *(u32x4*)&stage[swz(tid * 2) * 4]     = (u32x4){0, 0, 0, 0};
    *(u32x4*)&stage[swz(tid * 2 + 1) * 4] = (u32x4){0, 0, 0, 0};

    #pragma unroll 1
    for (int t = 0; t < TSEQ; ++t) {
        __syncthreads();   // stage(t) ready (written by wave0 last iter / pre-loop)

        float zx0 = 0.f, zx1 = 0.f, zx2 = 0.f, zx3 = 0.f;
        if (cc == 0) {   // x-projection prefetch (plain loads, hidden under dot)
            const _Float16* zp = zxp + (size_t)t * NR;
            zx0 = (float)zp[0];    zx1 = (float)zp[2048];
            zx2 = (float)zp[4096]; zx3 = (float)zp[6144];
        }

        // ---- dot: 4 gate-rows (of h-elem rg) x 64 cols per thread ----
        float acc[4] = {0.f, 0.f, 0.f, 0.f};
        #pragma unroll
        for (int i = 0; i < 8; ++i) {
            u32x4 ga = *(const u32x4*)&stage[swz(cc * 16 + 2 * i) * 4];
            u32x4 gb = *(const u32x4*)&stage[swz(cc * 16 + 2 * i + 1) * 4];
            const h2 h0  = __builtin_bit_cast(h2, (u32)((ga.x & 0xffffu) | (ga.y << 16)));
            const h2 h1  = __builtin_bit_cast(h2, (u32)((ga.z & 0xffffu) | (ga.w << 16)));
            const h2 h2v = __builtin_bit_cast(h2, (u32)((gb.x & 0xffffu) | (gb.y << 16)));
            const h2 h3  = __builtin_bit_cast(h2, (u32)((gb.z & 0xffffu) | (gb.w << 16)));
            #pragma unroll
            for (int q = 0; q < 4; ++q) {
                const h8 wv8 = wreg[q][i];
                acc[q] = __builtin_amdgcn_fdot2((h2){wv8[0], wv8[1]}, h0,  acc[q], false);
                acc[q] = __builtin_amdgcn_fdot2((h2){wv8[2], wv8[3]}, h1,  acc[q], false);
                acc[q] = __builtin_amdgcn_fdot2((h2){wv8[4], wv8[5]}, h2v, acc[q], false);
                acc[q] = __builtin_amdgcn_fdot2((h2){wv8[6], wv8[7]}, h3,  acc[q], false);
            }
        }
        // reduce across the 32 col-chunk lanes (stays within 32-lane halves)
        #pragma unroll
        for (int m = 16; m >= 1; m >>= 1) {
            #pragma unroll
            for (int q = 0; q < 4; ++q) acc[q] += __shfl_xor(acc[q], m, 64);
        }

        // ---- gate math + cell update + publish tag t+1, lane cc==0 ----
        if (cc == 0) {
            const float f  = sigmoidf_(acc[0] + zx0 + bias0);
            const float i_ = sigmoidf_(acc[1] + zx1 + bias1);
            const float g_ = tanhf_(acc[2] + zx2 + bias2);
            const float o  = sigmoidf_(acc[3] + zx3 + bias3);
            const float cn = f * c_reg + i_ * g_;
            c_reg = cn;
            const float hn = o * tanhf_(cn);
            const unsigned short hb =
                __builtin_bit_cast(unsigned short, (_Float16)hn);
            const u32 word = ((u32)(t + 1) << 16) | (u32)hb;
            u32* op = hword + (size_t)((t + 1) & 1) * HDIM + 8 * w + rg;
            asm volatile("global_atomic_swap %0, %1, off sc1"
                         :: "v"(op), "v"(word) : "memory");
            if (t == TSEQ - 1) hfin[8 * w + rg] = hn;
        }

        // ---- wave 0: late-burst detect + fetch + stage for step t+1 ----
        if (tid < 64 && t + 1 < TSEQ) {
            const u32 nexp = (u32)(t + 1) << 16;
            const size_t nslot = (size_t)((t + 1) & 1) * HDIM;
            const u32* sp = hword + nslot + (size_t)tid * 32;  // producers 4*tid..+3
            u32 s0, s1, s2, s3;
            for (;;) {
                asm volatile(
                    "global_load_dword %0, %4, off sc0 sc1\n\t"
                    "global_load_dword %1, %4, off offset:32 sc0 sc1\n\t"
                    "global_load_dword %2, %4, off offset:64 sc0 sc1\n\t"
                    "global_load_dword %3, %4, off offset:96 sc0 sc1\n\t"
                    "s_waitcnt vmcnt(0)"
                    : "=&v"(s0), "=&v"(s1), "=&v"(s2), "=&v"(s3)
                    : "v"(sp) : "memory");
                const u32 bad = ((s0 ^ nexp) | (s1 ^ nexp) | (s2 ^ nexp) | (s3 ^ nexp))
                                & 0xFFFF0000u;
                if (!bad) break;
            }
            // bulk fetch this lane's 128B (words 32*tid..+32) + full verify
            u32x4 F0, F1, F2, F3, F4, F5, F6, F7;
            for (;;) {
                asm volatile(
                    "global_load_dwordx4 %0, %8, off sc0 sc1\n\t"
                    "global_load_dwordx4 %1, %8, off offset:16 sc0 sc1\n\t"
                    "global_load_dwordx4 %2, %8, off offset:32 sc0 sc1\n\t"
                    "global_load_dwordx4 %3, %8, off offset:48 sc0 sc1\n\t"
                    "global_load_dwordx4 %4, %8, off offset:64 sc0 sc1\n\t"
                    "global_load_dwordx4 %5, %8, off offset:80 sc0 sc1\n\t"
                    "global_load_dwordx4 %6, %8, off offset:96 sc0 sc1\n\t"
                    "global_load_dwordx4 %7, %8, off offset:112 sc0 sc1\n\t"
                    "s_waitcnt vmcnt(0)"
                    : "=&v"(F0), "=&v"(F1), "=&v"(F2), "=&v"(F3),
                      "=&v"(F4), "=&v"(F5), "=&v"(F6), "=&v"(F7)
                    : "v"(sp) : "memory");
                u32 bad = (F0.x ^ nexp) | (F0.y ^ nexp) | (F0.z ^ nexp) | (F0.w ^ nexp);
                bad |= (F1.x ^ nexp) | (F1.y ^ nexp) | (F1.z ^ nexp) | (F1.w ^ nexp);
                bad |= (F2.x ^ nexp) | (F2.y ^ nexp) | (F2.z ^ nexp) | (F2.w ^ nexp);
                bad |= (F3.x ^ nexp) | (F3.y ^ nexp) | (F3.z ^ nexp) | (F3.w ^ nexp);
                bad |= (F4.x ^ nexp) | (F4.y ^ nexp) | (F4.z ^ nexp) | (F4.w ^ nexp);
                bad |= (F5.x ^ nexp) | (F5.y ^ nexp) | (F5.z ^ nexp) | (F5.w ^ nexp);
                bad |= (F6.x ^ nexp) | (F6.y ^ nexp) | (F6.z ^ nexp) | (F6.w ^ nexp);
                bad |= (F7.x ^ nexp) | (F7.y ^ nexp) | (F7.z ^ nexp) | (F7.w ^ nexp);
                if (!(bad & 0xFFFF0000u)) break;
                __builtin_amdgcn_s_sleep(1);
            }
            // stage 8 groups (32 words) swizzled for WG-wide reuse
            *(u32x4*)&stage[swz(tid * 8 + 0) * 4] = F0;
            *(u32x4*)&stage[swz(tid * 8 + 1) * 4] = F1;
            *(u32x4*)&stage[swz(tid * 8 + 2) * 4] = F2;
            *(u32x4*)&stage[swz(tid * 8 + 3) * 4] = F3;
            *(u32x4*)&stage[swz(tid * 8 + 4) * 4] = F4;
            *(u32x4*)&stage[swz(tid * 8 + 5) * 4] = F5;
            *(u32x4*)&stage[swz(tid * 8 + 6) * 4] = F6;
            *(u32x4*)&stage[swz(tid * 8 + 7) * 4] = F7;
        }
        // loop-top barrier publishes stage(t+1) to all waves
    }
}

// ---------------------------------------------------------------------------
// y[row] = by[row] + wy[row,:] . hfin
// ---------------------------------------------------------------------------
__global__ __launch_bounds__(256) void proj(
    const float* __restrict__ wy, const float* __restrict__ byv,
    const float* __restrict__ hfin, float* __restrict__ y)
{
    const int row = blockIdx.x;
    const float* wr = wy + (size_t)row * HDIM;
    float s = 0.f;
    for (int k = threadIdx.x * 4; k < HDIM; k += 256 * 4) {
        f4 wv = *(const f4*)&wr[k];
        f4 hv = *(const f4*)&hfin[k];
        s = fmaf(wv[0], hv[0], fmaf(wv[1], hv[1], fmaf(wv[2], hv[2], fmaf(wv[3], hv[3], s))));
    }
    #pragma unroll
    for (int m = 32; m >= 1; m >>= 1) s += __shfl_xor(s, m, 64);
    __shared__ float red[4];
    if ((threadIdx.x & 63) == 0) red[threadIdx.x >> 6] = s;
    __syncthreads();
    if (threadIdx.x == 0) y[row] = red[0] + red[1] + red[2] + red[3] + byv[row];
}

// ---------------------------------------------------------------------------
extern "C" void kernel_launch(void* const* d_in, const int* in_sizes, int n_in,
                              void* d_out, int out_size, void* d_ws, size_t ws_size,
                              hipStream_t stream)
{
    (void)in_sizes; (void)n_in; (void)out_size;
    const float* X   = (const float*)d_in[0];
    const float* wfp = (const float*)d_in[1];
    const float* bfv = (const float*)d_in[2];
    const float* wip = (const float*)d_in[3];
    const float* biv = (const float*)d_in[4];
    const float* wcp = (const float*)d_in[5];
    const float* bcv = (const float*)d_in[6];
    const float* wop = (const float*)d_in[7];
    const float* bov = (const float*)d_in[8];
    const float* wy  = (const float*)d_in[9];
    const float* byv = (const float*)d_in[10];
    float* y = (float*)d_out;

    char* ws = (char*)d_ws;
    const size_t need = ((size_t)64 << 20) + ((size_t)64 << 10);
    if (ws_size < need) return;  // fail visibly rather than corrupt

    _Float16* Zx  = (_Float16*)ws;                                   // 64 MiB
    u32* hword    = (u32*)(ws + ((size_t)64 << 20));                 // 16 KiB
    float* hfin   = (float*)(ws + ((size_t)64 << 20) + (16 << 10));  // 8 KiB

    // slot0 = (tag 0, h=0) == correct h_0; also kills cross-replay tag aliasing
    (void)hipMemsetAsync(hword, 0, 2 * HDIM * sizeof(u32), stream);
    gemm_zx<<<dim3(2048), dim3(256), 0, stream>>>(X, wfp, wip, wcp, wop, Zx);
    lstm_rec<<<dim3(256), dim3(256), 0, stream>>>(wfp, wip, wcp, wop,
                                                  bfv, biv, bcv, bov,
                                                  Zx, hword, hfin);
    proj<<<dim3(2048), dim3(256), 0, stream>>>(wy, byv, hfin, y);
}

// Round 14
// 9818.735 us; speedup vs baseline: 2.8899x; 2.2975x over previous
//
#include <hip/hip_runtime.h>
#include <hip/hip_fp16.h>

typedef _Float16 h8 __attribute__((ext_vector_type(8)));
typedef _Float16 h2 __attribute__((ext_vector_type(2)));
typedef float    f4 __attribute__((ext_vector_type(4)));
typedef unsigned int u32;
typedef u32 u32x4 __attribute__((ext_vector_type(4)));

#define HDIM 2048
#define FDIM 2048
#define TSEQ 4096
#define NR   8192   // 4*H rows of the fused gate matrix

__device__ __forceinline__ float sigmoidf_(float x) { return 1.0f / (1.0f + __expf(-x)); }
__device__ __forceinline__ float tanhf_(float x)    { return 1.0f - 2.0f / (1.0f + __expf(2.0f * x)); }

// Bank-swizzle for the LDS h-stage: 16B groups, low4 of group idx XOR'd with
// bits [7:4] -> reads at fixed i across cc spread over banks (2-4 way max).
__device__ __forceinline__ int swz(int g) { return (g & ~15) | ((g ^ (g >> 4)) & 15); }

// ---------------------------------------------------------------------------
// GEMM: Zx[t][j] = sum_k X[t][k] * w{g}[j&2047][2048+k],  g = j>>11
// M=4096(T) x N=8192(4H) x K=2048(F), fp16 MFMA 16x16x32, 128x128 tile.
// ---------------------------------------------------------------------------
__global__ __launch_bounds__(256) void gemm_zx(
    const float* __restrict__ X,
    const float* __restrict__ wfp, const float* __restrict__ wip,
    const float* __restrict__ wcp, const float* __restrict__ wop,
    _Float16* __restrict__ Zx)
{
    __shared__ __align__(16) _Float16 As[128 * 32];
    __shared__ __align__(16) _Float16 Bs[128 * 32];
    const int tid  = threadIdx.x;
    const int lane = tid & 63;
    const int wv   = tid >> 6;
    const int bm   = blockIdx.x & 31;   // 32 M-tiles
    const int bn   = blockIdx.x >> 5;   // 64 N-tiles
    const int m0 = bm * 128, n0 = bn * 128;
    const int g = n0 >> 11;             // 128-row tile never crosses a gate boundary
    const float* wsrc = (g == 0) ? wfp : (g == 1) ? wip : (g == 2) ? wcp : wop;
    const int nr0 = n0 & 2047;

    f4 acc[4][4];
    #pragma unroll
    for (int i = 0; i < 4; ++i)
        #pragma unroll
        for (int j = 0; j < 4; ++j) acc[i][j] = (f4){0.f, 0.f, 0.f, 0.f};

    const int wm = (wv >> 1) * 64, wn = (wv & 1) * 64;
    const int fr = lane & 15, kg = lane >> 4;

    for (int k0 = 0; k0 < FDIM; k0 += 32) {
        __syncthreads();
        #pragma unroll
        for (int r = 0; r < 2; ++r) {
            const int row = r * 64 + (tid >> 2);
            const int col = (tid & 3) * 8;
            const float* ax = &X[(size_t)(m0 + row) * FDIM + k0 + col];
            f4 a0 = *(const f4*)ax, a1 = *(const f4*)(ax + 4);
            h8 av = { (_Float16)a0[0], (_Float16)a0[1], (_Float16)a0[2], (_Float16)a0[3],
                      (_Float16)a1[0], (_Float16)a1[1], (_Float16)a1[2], (_Float16)a1[3] };
            *(h8*)&As[row * 32 + col] = av;
            const float* bx = &wsrc[(size_t)(nr0 + row) * 4096 + 2048 + k0 + col];
            f4 b0 = *(const f4*)bx, b1 = *(const f4*)(bx + 4);
            h8 bv = { (_Float16)b0[0], (_Float16)b0[1], (_Float16)b0[2], (_Float16)b0[3],
                      (_Float16)b1[0], (_Float16)b1[1], (_Float16)b1[2], (_Float16)b1[3] };
            *(h8*)&Bs[row * 32 + col] = bv;
        }
        __syncthreads();
        h8 af[4], bf[4];
        #pragma unroll
        for (int i = 0; i < 4; ++i) af[i] = *(const h8*)&As[(wm + i * 16 + fr) * 32 + kg * 8];
        #pragma unroll
        for (int j = 0; j < 4; ++j) bf[j] = *(const h8*)&Bs[(wn + j * 16 + fr) * 32 + kg * 8];
        #pragma unroll
        for (int i = 0; i < 4; ++i)
            #pragma unroll
            for (int j = 0; j < 4; ++j)
                acc[i][j] = __builtin_amdgcn_mfma_f32_16x16x32_f16(af[i], bf[j], acc[i][j], 0, 0, 0);
    }
    // C/D layout: col = lane&15 (N), row = (lane>>4)*4 + q (M)   [m89/m91]
    #pragma unroll
    for (int i = 0; i < 4; ++i)
        #pragma unroll
        for (int j = 0; j < 4; ++j)
            #pragma unroll
            for (int q = 0; q < 4; ++q) {
                const int row = m0 + wm + i * 16 + (lane >> 4) * 4 + q;
                const int col = n0 + wn + j * 16 + (lane & 15);
                Zx[(size_t)row * NR + col] = (_Float16)acc[i][j][q];
            }
}

// ---------------------------------------------------------------------------
// Persistent recurrent kernel, fence-free tag-in-word messaging (the R8
// empirical optimum, restored verbatim). hword: 2 slots x 2048 u32; word j of
// slot (t&1) = (t<<16)|fp16bits(h_t[j]). Producers publish via atomic_swap
// sc1 (executes at the device coherence point). Phase A: wave 0 polls 4B
// sentinels late-burst (contention throttle: one wave per CU, others parked
// at the barrier). Phase B: all 256 threads one-shot 32B bulk fetch + FULL
// per-word tag verify (correctness never rests on sentinel=>block
// visibility). 2-slot ring safety: producer reaches tag t+2 on a slot only
// after every WG consumed tag t. hword memset per launch: slot0=(tag0,h=0)
// == h_0, no cross-replay aliasing. Weights in VGPRs (static 4x64
// slice/thread); gate tail on 32 lanes + shfl combine; cell state in regs.
// ---------------------------------------------------------------------------
__global__ __launch_bounds__(256, 1) void lstm_rec(
    const float* __restrict__ wfp, const float* __restrict__ wip,
    const float* __restrict__ wcp, const float* __restrict__ wop,
    const float* __restrict__ bfv, const float* __restrict__ biv,
    const float* __restrict__ bcv, const float* __restrict__ bov,
    const _Float16* __restrict__ Zx,
    u32* __restrict__ hword,          // 2 * 2048 tagged words
    float* __restrict__ hfin)         // 2048 fp32
{
    __shared__ __align__(16) u32 stage[HDIM];  // 8 KiB staged h words
    __shared__ float z_lds[32];

    const int tid = threadIdx.x;
    const int w   = blockIdx.x;
    const int rg  = tid >> 5, cc = tid & 31;

    // ---- one-time: this thread's weight slice into VGPRs (static indexing) ----
    // rows rl = rg*4+q (gate rl>>3, elem rl&7), cols cc*64 + i*8 .. +8
    h8 wreg[4][8];
    #pragma unroll
    for (int q = 0; q < 4; ++q) {
        const int rl = rg * 4 + q;
        const int gg = rl >> 3, r8 = rl & 7;
        const float* src = ((gg == 0) ? wfp : (gg == 1) ? wip : (gg == 2) ? wcp : wop)
                           + (size_t)(8 * w + r8) * 4096 + cc * 64;
        #pragma unroll
        for (int i = 0; i < 8; ++i) {
            f4 a0 = *(const f4*)(src + i * 8);
            f4 a1 = *(const f4*)(src + i * 8 + 4);
            wreg[q][i] = (h8){ (_Float16)a0[0], (_Float16)a0[1], (_Float16)a0[2], (_Float16)a0[3],
                               (_Float16)a1[0], (_Float16)a1[1], (_Float16)a1[2], (_Float16)a1[3] };
        }
    }
    // ---- per-lane gate parameters (lanes 0..31: gate = tid>>3, elem = tid&7) ----
    float bias_g = 0.f;
    float c_reg  = 0.f;                       // cell state, valid in lanes 0..7
    const _Float16* zx_ptr = Zx;              // dummy init
    if (tid < 32) {
        const int gg = tid >> 3, e = tid & 7;
        const float* bsrc = (gg == 0) ? bfv : (gg == 1) ? biv : (gg == 2) ? bcv : bov;
        bias_g = bsrc[8 * w + e];
        zx_ptr = Zx + (size_t)gg * 2048 + 8 * w + e;   // + t*NR per step
    }

    #pragma unroll 1
    for (int t = 0; t < TSEQ; ++t) {
        float zx_g = 0.f;
        if (tid < 32) zx_g = (float)zx_ptr[(size_t)t * NR];   // prefetch early

        const u32 texp = (u32)t << 16;
        const size_t slotbase = (size_t)(t & 1) * HDIM;

        // ---- Phase A: wave 0 polls 4B sentinels (one per producer WG) ----
        if (tid < 64) {
            const u32* sp = hword + slotbase + (size_t)tid * 32;  // producers 4*tid..+3
            u32 s0, s1, s2, s3;
            for (;;) {
                asm volatile(
                    "global_load_dword %0, %4, off sc0 sc1\n\t"
                    "global_load_dword %1, %4, off offset:32 sc0 sc1\n\t"
                    "global_load_dword %2, %4, off offset:64 sc0 sc1\n\t"
                    "global_load_dword %3, %4, off offset:96 sc0 sc1\n\t"
                    "s_waitcnt vmcnt(0)"
                    : "=&v"(s0), "=&v"(s1), "=&v"(s2), "=&v"(s3)
                    : "v"(sp) : "memory");
                const u32 bad = ((s0 ^ texp) | (s1 ^ texp) | (s2 ^ texp) | (s3 ^ texp))
                                & 0xFFFF0000u;
                if (!bad) break;
            }
        }
        __syncthreads();   // all data (sentinel-wise) published at L3

        // ---- Phase B: one-shot bulk fetch + full tag verify ----
        const u32* p = hword + slotbase + (size_t)tid * 8;
        u32x4 A, B;
        for (;;) {
            asm volatile(
                "global_load_dwordx4 %0, %2, off sc0 sc1\n\t"
                "global_load_dwordx4 %1, %2, off offset:16 sc0 sc1\n\t"
                "s_waitcnt vmcnt(0)"
                : "=&v"(A), "=&v"(B) : "v"(p) : "memory");
            const u32 bad = ((A.x ^ texp) | (A.y ^ texp) | (A.z ^ texp) | (A.w ^ texp) |
                             (B.x ^ texp) | (B.y ^ texp) | (B.z ^ texp) | (B.w ^ texp))
                            & 0xFFFF0000u;
            if (!bad) break;
            __builtin_amdgcn_s_sleep(1);
        }
        // stage the 8 fresh words (2 swizzled 16B groups) for WG-wide reuse
        *(u32x4*)&stage[swz(tid * 2) * 4]     = A;
        *(u32x4*)&stage[swz(tid * 2 + 1) * 4] = B;
        __syncthreads();

        // ---- dot: 4 rows x 64 cols per thread, weights in VGPRs ----
        float acc[4] = {0.f, 0.f, 0.f, 0.f};
        #pragma unroll
        for (int i = 0; i < 8; ++i) {
            u32x4 ga = *(const u32x4*)&stage[swz(cc * 16 + 2 * i) * 4];
            u32x4 gb = *(const u32x4*)&stage[swz(cc * 16 + 2 * i + 1) * 4];
            const h2 h0  = __builtin_bit_cast(h2, (u32)((ga.x & 0xffffu) | (ga.y << 16)));
            const h2 h1  = __builtin_bit_cast(h2, (u32)((ga.z & 0xffffu) | (ga.w << 16)));
            const h2 h2v = __builtin_bit_cast(h2, (u32)((gb.x & 0xffffu) | (gb.y << 16)));
            const h2 h3  = __builtin_bit_cast(h2, (u32)((gb.z & 0xffffu) | (gb.w << 16)));
            #pragma unroll
            for (int q = 0; q < 4; ++q) {
                const h8 wv8 = wreg[q][i];
                acc[q] = __builtin_amdgcn_fdot2((h2){wv8[0], wv8[1]}, h0,  acc[q], false);
                acc[q] = __builtin_amdgcn_fdot2((h2){wv8[2], wv8[3]}, h1,  acc[q], false);
                acc[q] = __builtin_amdgcn_fdot2((h2){wv8[4], wv8[5]}, h2v, acc[q], false);
                acc[q] = __builtin_amdgcn_fdot2((h2){wv8[6], wv8[7]}, h3,  acc[q], false);
            }
        }
        // reduce across the 32 col-chunk lanes (stays within 32-lane halves)
        #pragma unroll
        for (int m = 16; m >= 1; m >>= 1) {
            #pragma unroll
            for (int q = 0; q < 4; ++q) acc[q] += __shfl_xor(acc[q], m, 64);
        }
        if (cc == 0) {
            #pragma unroll
            for (int q = 0; q < 4; ++q) z_lds[rg * 4 + q] = acc[q];  // idx = gate*8+e
        }
        __syncthreads();

        // ---- gate tail: 32 lanes, one activation each; combine on lanes 0..7 ----
        if (tid < 32) {
            const float zsum = z_lds[tid] + zx_g + bias_g;
            const int gg = tid >> 3;
            const float act = (gg == 2) ? tanhf_(zsum) : sigmoidf_(zsum);
            const int e = tid & 7;
            const float ai = __shfl(act, e + 8, 64);
            const float ag = __shfl(act, e + 16, 64);
            const float ao = __shfl(act, e + 24, 64);
            if (tid < 8) {
                const float cn = act * c_reg + ai * ag;   // act == f gate here
                c_reg = cn;
                const float hn = ao * tanhf_(cn);
                const unsigned short hb =
                    __builtin_bit_cast(unsigned short, (_Float16)hn);
                const u32 word = ((u32)(t + 1) << 16) | (u32)hb;
                u32* op = hword + (size_t)((t + 1) & 1) * HDIM + 8 * w + tid;
                asm volatile("global_atomic_swap %0, %1, off sc1"
                             :: "v"(op), "v"(word) : "memory");
                if (t == TSEQ - 1) hfin[8 * w + tid] = hn;
            }
        }
    }
}

// ---------------------------------------------------------------------------
// y[row] = by[row] + wy[row,:] . hfin
// ---------------------------------------------------------------------------
__global__ __launch_bounds__(256) void proj(
    const float* __restrict__ wy, const float* __restrict__ byv,
    const float* __restrict__ hfin, float* __restrict__ y)
{
    const int row = blockIdx.x;
    const float* wr = wy + (size_t)row * HDIM;
    float s = 0.f;
    for (int k = threadIdx.x * 4; k < HDIM; k += 256 * 4) {
        f4 wv = *(const f4*)&wr[k];
        f4 hv = *(const f4*)&hfin[k];
        s = fmaf(wv[0], hv[0], fmaf(wv[1], hv[1], fmaf(wv[2], hv[2], fmaf(wv[3], hv[3], s))));
    }
    #pragma unroll
    for (int m = 32; m >= 1; m >>= 1) s += __shfl_xor(s, m, 64);
    __shared__ float red[4];
    if ((threadIdx.x & 63) == 0) red[threadIdx.x >> 6] = s;
    __syncthreads();
    if (threadIdx.x == 0) y[row] = red[0] + red[1] + red[2] + red[3] + byv[row];
}

// ---------------------------------------------------------------------------
extern "C" void kernel_launch(void* const* d_in, const int* in_sizes, int n_in,
                              void* d_out, int out_size, void* d_ws, size_t ws_size,
                              hipStream_t stream)
{
    (void)in_sizes; (void)n_in; (void)out_size;
    const float* X   = (const float*)d_in[0];
    const float* wfp = (const float*)d_in[1];
    const float* bfv = (const float*)d_in[2];
    const float* wip = (const float*)d_in[3];
    const float* biv = (const float*)d_in[4];
    const float* wcp = (const float*)d_in[5];
    const float* bcv = (const float*)d_in[6];
    const float* wop = (const float*)d_in[7];
    const float* bov = (const float*)d_in[8];
    const float* wy  = (const float*)d_in[9];
    const float* byv = (const float*)d_in[10];
    float* y = (float*)d_out;

    char* ws = (char*)d_ws;
    const size_t need = ((size_t)64 << 20) + ((size_t)64 << 10);
    if (ws_size < need) return;  // fail visibly rather than corrupt

    _Float16* Zx  = (_Float16*)ws;                                   // 64 MiB
    u32* hword    = (u32*)(ws + ((size_t)64 << 20));                 // 16 KiB
    float* hfin   = (float*)(ws + ((size_t)64 << 20) + (16 << 10));  // 8 KiB

    // slot0 = (tag 0, h=0) == correct h_0; also kills cross-replay tag aliasing
    (void)hipMemsetAsync(hword, 0, 2 * HDIM * sizeof(u32), stream);
    gemm_zx<<<dim3(2048), dim3(256), 0, stream>>>(X, wfp, wip, wcp, wop, Zx);
    lstm_rec<<<dim3(256), dim3(256), 0, stream>>>(wfp, wip, wcp, wop,
                                                  bfv, biv, bcv, bov,
                                                  Zx, hword, hfin);
    proj<<<dim3(2048), dim3(256), 0, stream>>>(wy, byv, hfin, y);
}